// Round 11
// baseline (66.591 us; speedup 1.0000x reference)
//
#include <hip/hip_runtime.h>

// SSIM fused: [16,1,1024,1024] fp32, 11-tap separable Gaussian.
// V-phase: 1 col/thread, register ring of 11 rows x packed float4 channels
//          {a, b, a^2+b^2, a*b}; one ds_write_b128 per pixel.
// H-phase: q = t>>5 (4 rows), run = t&31 (4-col runs, S0 = 4*run); swizzled
//          b128 reads are max 2-way conflicted (free per m136).
// Pipeline: RPS=4 stages, double-buffered lds[2][4][128] (16 KB total);
//          ONE barrier per stage; stage st+1's 8 global loads prefetched
//          into registers before H(st) (~900 cy of work hides HBM latency).
// TH=64 rows/block amortizes the ring prologue and keeps FETCH at ~99 MB.
// No min-occupancy launch_bounds arg (r5/r6: it forces spills).
// Deterministic two-stage reduction -> d_out[0].

typedef float f4 __attribute__((ext_vector_type(4)));

#define W      1024
#define H      1024
#define NIMG   16
#define HALO   5
#define BX     128                 // threads = LDS slots (input cols) per block
#define OUTW   118                 // output cols per block
#define RPS    4                   // rows per stage
#define NSTG   16                  // stages per block
#define TH     (RPS*NSTG)          // 64 output rows per block
#define GX     9                   // ceil(1024/118)
#define GY     (H/TH)              // 16
#define NBLK   (GX*GY*NIMG)        // 2304

__device__ __forceinline__ int swz(int s) { return s ^ ((s >> 3) & 7); }

template<bool INT>
__device__ __forceinline__ void pf_row(const float* __restrict__ p1,
                                       const float* __restrict__ p2,
                                       int j, int c, bool cOK,
                                       float& a, float& b)
{
    if (INT) {
        a = p1[(size_t)j * W + c];
        b = p2[(size_t)j * W + c];
    } else {
        const bool ok = cOK && ((unsigned)j < H);
        a = ok ? p1[(size_t)j * W + c] : 0.0f;
        b = ok ? p2[(size_t)j * W + c] : 0.0f;
    }
}

__device__ __forceinline__ f4 pack_ch(float a, float b)
{
    f4 v;
    v.x = a; v.y = b;
    v.z = fmaf(a, a, b * b);
    v.w = a * b;
    return v;
}

// V-blur RPS rows from prefetched registers; write LDS buf.
__device__ __forceinline__ void vstage_reg(const float* __restrict__ w,
                                           const float (&pa)[RPS], const float (&pb)[RPS],
                                           f4 (&ring)[11], f4 (*buf)[BX], int ws_)
{
#pragma unroll
    for (int rr = 0; rr < RPS; ++rr) {
#pragma unroll
        for (int k = 0; k < 10; ++k) ring[k] = ring[k + 1];
        ring[10] = pack_ch(pa[rr], pb[rr]);

        f4 acc = w[5] * ring[5];
#pragma unroll
        for (int k = 0; k < 5; ++k)
            acc += w[k] * (ring[k] + ring[10 - k]);

        buf[rr][ws_] = acc;
    }
}

template<bool INT>
__device__ float tile(const float* __restrict__ p1,
                      const float* __restrict__ p2,
                      const float* __restrict__ w,
                      int cb, int r0, int t,
                      f4 (*lds)[RPS][BX])
{
    const int  c   = cb + t;                 // this thread's input col
    const bool cOK = INT || ((unsigned)c < W);

    // ring[1..10] <- rows r0-5 .. r0+4 (packed 4 channels)
    f4 ring[11];
#pragma unroll
    for (int k = 0; k < 10; ++k) {
        float a, b;
        pf_row<INT>(p1, p2, r0 - HALO + k, c, cOK, a, b);
        ring[k + 1] = pack_ch(a, b);
    }

    // h-task mapping (power-of-2, phase-group aligned)
    const int  q   = t >> 5;                 // staged row index 0..3
    const int  run = t & 31;                 // column run index
    const int  S0  = 4 * run;                // first LDS slot of run
    const bool hT  = (run < 30);             // runs 30,31: no valid outputs
    const int  ws_ = swz(t);                 // v-phase write slot

    float pa[RPS], pb[RPS];

    // prologue: prefetch + V-blur stage 0 into buf 0
#pragma unroll
    for (int rr = 0; rr < RPS; ++rr)
        pf_row<INT>(p1, p2, r0 + HALO + rr, c, cOK, pa[rr], pb[rr]);
    vstage_reg(w, pa, pb, ring, lds[0], ws_);
    __syncthreads();

    float tsum = 0.0f;

    for (int st = 0; st < NSTG; ++st) {
        // ---- prefetch stage st+1 rows (VMEM issue; consumed below) ----
        if (st + 1 < NSTG) {
#pragma unroll
            for (int rr = 0; rr < RPS; ++rr)
                pf_row<INT>(p1, p2, r0 + (st + 1) * RPS + HALO + rr, c, cOK,
                            pa[rr], pb[rr]);
        }

        // ---- H phase for current stage (hides prefetch latency) ----
        if (hT) {
            f4 (*buf)[BX] = lds[st & 1];
            f4 o[4] = {};
#pragma unroll
            for (int i = 0; i < 14; ++i) {
                int sIdx = S0 + i;                       // run29: up to 129
                sIdx = (sIdx < BX) ? sIdx : (BX - 1);    // clamp: feeds only invalid outs
                const f4 u = buf[q][swz(sIdx)];
#pragma unroll
                for (int oo = 0; oo < 4; ++oo) {
                    const int k = i - oo;
                    if (k >= 0 && k < 11)
                        o[oo] += w[k] * u;
                }
            }

            const float C1f = 0.0001f, C2f = 0.0009f;
#pragma unroll
            for (int oo = 0; oo < 4; ++oo) {
                const int rel = S0 + oo;                 // rel output col
                const bool valid = (rel < OUTW) &&
                                   (INT || (cb + HALO + rel) < W);
                if (valid) {
                    const float m1 = o[oo].x, m2 = o[oo].y;
                    const float qq = o[oo].z, pp = o[oo].w;
                    const float mu12 = m1 * m2, m1s = m1 * m1, m2s = m2 * m2;
                    const float s12 = pp - mu12;
                    const float ssq = qq - m1s - m2s;
                    const float num = (2.f * mu12 + C1f) * (2.f * s12 + C2f);
                    const float den = (m1s + m2s + C1f) * (ssq + C2f);
                    tsum += num * __builtin_amdgcn_rcpf(den);
                }
            }
        }

        // ---- V phase for next stage into the OTHER buffer ----
        if (st + 1 < NSTG)
            vstage_reg(w, pa, pb, ring, lds[(st + 1) & 1], ws_);

        __syncthreads();   // one barrier/stage: RAW on buf^1, WAR on buf
    }
    return tsum;
}

__global__ __launch_bounds__(BX) void ssim_main(const float* __restrict__ img1,
                                                const float* __restrict__ img2,
                                                const float* __restrict__ win,
                                                float* __restrict__ partials)
{
    __shared__ f4 lds[2][RPS][BX];           // 16 KB, double-buffered

    const int t  = threadIdx.x;
    const int n  = blockIdx.z;
    const int bx = blockIdx.x;
    const int gy = blockIdx.y;
    const int cb = bx * OUTW - HALO;         // input col of LDS slot 0
    const int r0 = gy * TH;

    const float* __restrict__ p1 = img1 + (size_t)n * (size_t)(W * H);
    const float* __restrict__ p2 = img2 + (size_t)n * (size_t)(W * H);

    float w[11];
#pragma unroll
    for (int k = 0; k < 11; ++k)
        w[k] = __int_as_float(__builtin_amdgcn_readfirstlane(__float_as_int(win[k])));

    const bool interior = (cb >= 0) && (cb + BX <= W) &&
                          (r0 >= HALO) && (r0 + TH - 1 + HALO < H);

    float tsum = interior ? tile<true >(p1, p2, w, cb, r0, t, lds)
                          : tile<false>(p1, p2, w, cb, r0, t, lds);

    // block reduction (2 waves of 64); reuse staging LDS as scratch
#pragma unroll
    for (int off = 32; off > 0; off >>= 1)
        tsum += __shfl_down(tsum, off, 64);

    float* red = (float*)lds;                // safe: trailing barrier in tile()
    if ((t & 63) == 0) red[t >> 6] = tsum;
    __syncthreads();
    if (t == 0)
        partials[((size_t)n * GY + gy) * GX + bx] = red[0] + red[1];
}

__global__ __launch_bounds__(256) void ssim_finalize(const float* __restrict__ partials,
                                                     float* __restrict__ out)
{
    double s = 0.0;
    for (int i = threadIdx.x; i < NBLK; i += 256) s += (double)partials[i];
#pragma unroll
    for (int off = 32; off > 0; off >>= 1)
        s += __shfl_down(s, off, 64);

    __shared__ double ws[4];
    if ((threadIdx.x & 63) == 0) ws[threadIdx.x >> 6] = s;
    __syncthreads();
    if (threadIdx.x == 0) {
        const double tt = ws[0] + ws[1] + ws[2] + ws[3];
        out[0] = (float)(tt / (double)((size_t)NIMG * W * H));
    }
}

extern "C" void kernel_launch(void* const* d_in, const int* in_sizes, int n_in,
                              void* d_out, int out_size, void* d_ws, size_t ws_size,
                              hipStream_t stream)
{
    const float* img1 = (const float*)d_in[0];
    const float* img2 = (const float*)d_in[1];
    const float* win  = (const float*)d_in[2];
    float* partials   = (float*)d_ws;
    float* out        = (float*)d_out;

    dim3 grid(GX, GY, NIMG);
    dim3 block(BX);
    ssim_main<<<grid, block, 0, stream>>>(img1, img2, win, partials);
    ssim_finalize<<<1, 256, 0, stream>>>(partials, out);
}

// Round 12
// 61.064 us; speedup vs baseline: 1.0905x; 1.0905x over previous
//
#include <hip/hip_runtime.h>

// SSIM fused: [16,1,1024,1024] fp32, 11-tap separable Gaussian.
// BARRIER-FREE inner loop: each 64-lane wave owns a private 64-col x 64-row
// tile and an 8 KB LDS slab. Per 8-row stage: V-blur (register ring of 11
// packed f4 channels {a,b,a^2+b^2,ab}; ds_write_b128 stride-1) -> register
// prefetch of next stage's rows -> H-blur (q=lane>>3, run=lane&7, 7-output
// runs; 17 ds_read_b128 at slot stride 7 -> 28r mod 32 covers all 8
// bank-groups: conflict-free, NO swizzle). Intra-wave LDS RAW/WAR ordering is
// HW-guaranteed (in-order DS per wave) — no __syncthreads in the hot loop, so
// ~20 waves/CU drift freely and VALU/DS/VMEM overlap.
// No min-occupancy launch_bounds arg (r5/r6: forces spills).
// Deterministic reduction: per-wave partial -> finalize kernel -> d_out[0].

typedef float f4 __attribute__((ext_vector_type(4)));

#define W      1024
#define H      1024
#define NIMG   16
#define HALO   5
#define TW     64                  // input cols per wave tile (LDS slots)
#define TOW    54                  // output cols per wave tile
#define RPS    8                   // rows per stage
#define NSTG   8                   // stages per wave
#define TH     (RPS*NSTG)          // 64 output rows per wave
#define NTX    19                  // ceil(1024/54)
#define NTY    (H/TH)              // 16
#define WPB    4                   // waves per block
#define BX     (WPB*64)            // 256 threads
#define NWAVE  (NTX*NTY*NIMG)      // 4864
#define NBLK   (NWAVE/WPB)         // 1216

template<bool INT>
__device__ __forceinline__ void pf_row(const float* __restrict__ p1,
                                       const float* __restrict__ p2,
                                       int j, int c, bool cOK,
                                       float& a, float& b)
{
    if (INT) {
        a = p1[(size_t)j * W + c];
        b = p2[(size_t)j * W + c];
    } else {
        const bool ok = cOK && ((unsigned)j < H);
        a = ok ? p1[(size_t)j * W + c] : 0.0f;
        b = ok ? p2[(size_t)j * W + c] : 0.0f;
    }
}

__device__ __forceinline__ f4 pack_ch(float a, float b)
{
    f4 v;
    v.x = a; v.y = b;
    v.z = fmaf(a, a, b * b);
    v.w = a * b;
    return v;
}

template<bool INT>
__device__ float wave_tile(const float* __restrict__ p1,
                           const float* __restrict__ p2,
                           const float* __restrict__ w,
                           int cb, int r0, int lane, int obase,
                           f4 (*lds)[TW])
{
    const int  c   = cb + lane;              // this lane's input col
    const bool cOK = INT || ((unsigned)c < W);

    // ring[1..10] <- rows r0-5 .. r0+4 (packed 4 channels)
    f4 ring[11];
#pragma unroll
    for (int k = 0; k < 10; ++k) {
        float a, b;
        pf_row<INT>(p1, p2, r0 - HALO + k, c, cOK, a, b);
        ring[k + 1] = pack_ch(a, b);
    }

    // H mapping: lane -> (staged row q, 7-col run)
    const int q   = lane >> 3;               // 0..7
    const int run = lane & 7;                // 0..7
    const int S0  = 7 * run;                 // first slot of run (stride 7!)

    // prefetch stage 0 rows
    float pa[RPS], pb[RPS];
#pragma unroll
    for (int rr = 0; rr < RPS; ++rr)
        pf_row<INT>(p1, p2, r0 + HALO + rr, c, cOK, pa[rr], pb[rr]);

    float tsum = 0.0f;

    for (int st = 0; st < NSTG; ++st) {
        // ---- V phase: consume prefetched rows, write own LDS slab ----
#pragma unroll
        for (int rr = 0; rr < RPS; ++rr) {
#pragma unroll
            for (int k = 0; k < 10; ++k) ring[k] = ring[k + 1];
            ring[10] = pack_ch(pa[rr], pb[rr]);

            f4 acc = w[5] * ring[5];
#pragma unroll
            for (int k = 0; k < 5; ++k)
                acc += w[k] * (ring[k] + ring[10 - k]);

            lds[rr][lane] = acc;
        }

        // ---- prefetch stage st+1 (latency hidden under H below) ----
        if (st + 1 < NSTG) {
#pragma unroll
            for (int rr = 0; rr < RPS; ++rr)
                pf_row<INT>(p1, p2, r0 + (st + 1) * RPS + HALO + rr, c, cOK,
                            pa[rr], pb[rr]);
        }

        // ---- H phase: row q, outputs S0..S0+6 (in-order DS => RAW safe) ----
        {
            f4 o[7] = {};
#pragma unroll
            for (int i = 0; i < 17; ++i) {
                int s = S0 + i;                      // run 7: up to 65
                s = (s < TW) ? s : (TW - 1);         // clamp: feeds masked outs only
                const f4 u = lds[q][s];
#pragma unroll
                for (int oo = 0; oo < 7; ++oo) {
                    const int k = i - oo;
                    if (k >= 0 && k < 11)
                        o[oo] += w[k] * u;
                }
            }

            const float C1f = 0.0001f, C2f = 0.0009f;
#pragma unroll
            for (int oo = 0; oo < 7; ++oo) {
                const int rel = S0 + oo;
                const bool valid = (rel < TOW) && (INT || (obase + rel) < W);
                if (valid) {
                    const float m1 = o[oo].x, m2 = o[oo].y;
                    const float qq = o[oo].z, pp = o[oo].w;
                    const float mu12 = m1 * m2, m1s = m1 * m1, m2s = m2 * m2;
                    const float s12 = pp - mu12;
                    const float ssq = qq - m1s - m2s;
                    const float num = (2.f * mu12 + C1f) * (2.f * s12 + C2f);
                    const float den = (m1s + m2s + C1f) * (ssq + C2f);
                    tsum += num * __builtin_amdgcn_rcpf(den);
                }
            }
        }
    }
    return tsum;
}

__global__ __launch_bounds__(BX) void ssim_main(const float* __restrict__ img1,
                                                const float* __restrict__ img2,
                                                const float* __restrict__ win,
                                                float* __restrict__ partials)
{
    __shared__ f4 lds[WPB][RPS][TW];         // 4 x 8 KB private wave slabs

    const int t    = threadIdx.x;
    const int wid  = t >> 6;
    const int lane = t & 63;
    const int gw   = blockIdx.x * WPB + wid; // global wave id

    // gw -> (img, gy, tx); tx fastest so neighboring waves share halo in L2
    const int img = gw / (NTX * NTY);
    const int rem = gw - img * (NTX * NTY);
    const int gy  = rem / NTX;
    const int tx  = rem - gy * NTX;

    const int cb    = tx * TOW - HALO;       // input col of LDS slot 0
    const int obase = tx * TOW;              // abs col of output 0
    const int r0    = gy * TH;

    const float* __restrict__ p1 = img1 + (size_t)img * (size_t)(W * H);
    const float* __restrict__ p2 = img2 + (size_t)img * (size_t)(W * H);

    float w[11];
#pragma unroll
    for (int k = 0; k < 11; ++k)
        w[k] = __int_as_float(__builtin_amdgcn_readfirstlane(__float_as_int(win[k])));

    const bool interior = (cb >= 0) && (cb + TW <= W) &&
                          (r0 >= HALO) && (r0 + TH - 1 + HALO < H);

    float tsum = interior
               ? wave_tile<true >(p1, p2, w, cb, r0, lane, obase, lds[wid])
               : wave_tile<false>(p1, p2, w, cb, r0, lane, obase, lds[wid]);

    // wave-private reduction; one store per wave — still no barrier
#pragma unroll
    for (int off = 32; off > 0; off >>= 1)
        tsum += __shfl_down(tsum, off, 64);

    if (lane == 0)
        partials[gw] = tsum;
}

__global__ __launch_bounds__(256) void ssim_finalize(const float* __restrict__ partials,
                                                     float* __restrict__ out)
{
    double s = 0.0;
    for (int i = threadIdx.x; i < NWAVE; i += 256) s += (double)partials[i];
#pragma unroll
    for (int off = 32; off > 0; off >>= 1)
        s += __shfl_down(s, off, 64);

    __shared__ double ws[4];
    if ((threadIdx.x & 63) == 0) ws[threadIdx.x >> 6] = s;
    __syncthreads();
    if (threadIdx.x == 0) {
        const double tt = ws[0] + ws[1] + ws[2] + ws[3];
        out[0] = (float)(tt / (double)((size_t)NIMG * W * H));
    }
}

extern "C" void kernel_launch(void* const* d_in, const int* in_sizes, int n_in,
                              void* d_out, int out_size, void* d_ws, size_t ws_size,
                              hipStream_t stream)
{
    const float* img1 = (const float*)d_in[0];
    const float* img2 = (const float*)d_in[1];
    const float* win  = (const float*)d_in[2];
    float* partials   = (float*)d_ws;
    float* out        = (float*)d_out;

    ssim_main<<<NBLK, BX, 0, stream>>>(img1, img2, win, partials);
    ssim_finalize<<<1, 256, 0, stream>>>(partials, out);
}